// Round 12
// baseline (230.126 us; speedup 1.0000x reference)
//
#include <hip/hip_runtime.h>
#include <hip/hip_bf16.h>
#include <hip/hip_fp8.h>

#define N_ROWS 4096
#define TWO_N 8192
#define DIM 512                             // elements per row; fp8 row = 512 B
#define BKB 64                              // K bytes per iter in fp8
#define NKS (DIM / BKB)                     // 8 K-steps
#define NBLK 2080
#define INV_T 14.285714285714286f           // 1/0.07
#define LOG2E 1.4426950408889634f
#define C_LOG2E 20.60992915555662f          // (1/0.07)*log2(e)
#define INV_SQRT_T 3.7796447300922722f      // 1/sqrt(0.07)

typedef float f32x4 __attribute__((ext_vector_type(4)));
typedef long fp8x8;                          // 8 fp8 = one 64-bit MFMA operand
typedef long fp8x8x2 __attribute__((ext_vector_type(2)));   // b128 = 2 operands

#define ASYNC_COPY16(gp, lp)                                                     \
  __builtin_amdgcn_global_load_lds((const __attribute__((address_space(1))) void*)(gp), \
                                   (__attribute__((address_space(3))) void*)(lp), 16, 0, 0)

#define VMCNT(n) asm volatile("s_waitcnt vmcnt(" #n ")" ::: "memory")

// Wave-per-row prep: float4 loads, butterfly shuffle reduce, fp8 e4m3 pack.
// Zn is stored K-PERMUTED: within each 64B k-block, 8B slot l (k=l*8..l*8+7)
// is placed at position (l&3)*16 + (l>>2)*8 (order [0,4,1,5,2,6,3,7]) so the
// two operands MFMA-lane q needs (slots q, q+4) are ADJACENT -> one b128
// read per fragment pair in k_lse. Exact: a global k-permutation of the
// Gram matrix inner dim, applied identically to A and B.
// posbuf (the subtracted positive) stays FP32-exact. Also zeroes rowsum+done.
__global__ __launch_bounds__(256) void k_prep(const float* __restrict__ z1,
                                              const float* __restrict__ z2,
                                              unsigned char* __restrict__ zn,
                                              float* __restrict__ posbuf,
                                              float* __restrict__ rowsum,
                                              int* __restrict__ done) {
  const int t = threadIdx.x;
  const int wv = t >> 6, lane = t & 63;
  const int r = blockIdx.x * 4 + wv;
  if (blockIdx.x < 32) rowsum[blockIdx.x * 256 + t] = 0.f;   // 32*256 = 8192
  if (blockIdx.x == 32 && t == 0) *done = 0;

  const float4* p1 = reinterpret_cast<const float4*>(z1 + (size_t)r * DIM) + (lane << 1);
  const float4* p2 = reinterpret_cast<const float4*>(z2 + (size_t)r * DIM) + (lane << 1);
  float4 a0 = p1[0], a1 = p1[1];
  float4 b0 = p2[0], b1 = p2[1];

  float s1 = a0.x * a0.x + a0.y * a0.y + a0.z * a0.z + a0.w * a0.w
           + a1.x * a1.x + a1.y * a1.y + a1.z * a1.z + a1.w * a1.w;
  float s2 = b0.x * b0.x + b0.y * b0.y + b0.z * b0.z + b0.w * b0.w
           + b1.x * b1.x + b1.y * b1.y + b1.z * b1.z + b1.w * b1.w;
  float sd = a0.x * b0.x + a0.y * b0.y + a0.z * b0.z + a0.w * b0.w
           + a1.x * b1.x + a1.y * b1.y + a1.z * b1.z + a1.w * b1.w;
#pragma unroll
  for (int off = 1; off < 64; off <<= 1) {
    s1 += __shfl_xor(s1, off, 64);
    s2 += __shfl_xor(s2, off, 64);
    sd += __shfl_xor(sd, off, 64);
  }
  const float sc1 = INV_SQRT_T / fmaxf(sqrtf(s1), 1e-8f);
  const float sc2 = INV_SQRT_T / fmaxf(sqrtf(s2), 1e-8f);

  float va[8] = {a0.x, a0.y, a0.z, a0.w, a1.x, a1.y, a1.z, a1.w};
  float vb[8] = {b0.x, b0.y, b0.z, b0.w, b1.x, b1.y, b1.z, b1.w};
  unsigned long long pa = 0, pb = 0;
#pragma unroll
  for (int d = 0; d < 8; d++) {
    __hip_fp8_e4m3 qa(va[d] * sc1);
    __hip_fp8_e4m3 qb(vb[d] * sc2);
    pa |= (unsigned long long)qa.__x << (8 * d);
    pb |= (unsigned long long)qb.__x << (8 * d);
  }
  // lane covers k = lane*8..+7 -> block = lane>>3, slot l = lane&7,
  // permuted position = block*64 + (l&3)*16 + (l>>2)*8
  const int pofs = (lane >> 3) * 64 + (lane & 3) * 16 + ((lane >> 2) & 1) * 8;
  *reinterpret_cast<unsigned long long*>(zn + (size_t)r * DIM + pofs) = pa;
  *reinterpret_cast<unsigned long long*>(zn + (size_t)(r + N_ROWS) * DIM + pofs) = pb;

  if (lane == 0) posbuf[r] = sd * sc1 * sc2;   // fp32-exact cos(z1_r,z2_r)/T
}

// ---------------------------------------------------------------------------
// Flash-LSE GEMM over upper-triangle 128x128 tiles -- FP8 e4m3, b128 reads.
// CHAMPION BODY = r10 verbatim (57.4us): 3 LDS buffers 48KB -> 3 blocks/CU,
// counted VMCNT(4) (2-iter slack, full drain only at tail), raw s_barrier,
// stage-after-barrier, XCD-bijective block swizzle, K-permuted global layout
// + granule XOR swizzle (measured 0 bank conflicts), 8 ds_read_b128 + 32
// MFMA per iter. r11's barrier-free experiment REGRESSED (67.5us, 2 blk/CU)
// -- convoy theory refuted; this skeleton is the verified local optimum.
//
// THIS ROUND'S ONLY CHANGE: k_final folded in via last-block ticket
// (total-minus-k_lse has been a constant ~60us across 12 rounds -- launch
// boundary overhead is now the largest addressable cost). No spin loops:
// stream order guarantees k_prep zeroes `done` before any k_lse block runs.
// ---------------------------------------------------------------------------
__global__ __launch_bounds__(256, 3) void k_lse(const unsigned char* __restrict__ Zn,
                                                float* __restrict__ rowsum,
                                                const float* __restrict__ posbuf,
                                                int* __restrict__ done,
                                                float* __restrict__ out) {
  __shared__ char smem[49152] __attribute__((aligned(16)));
  __shared__ float red[4];
  __shared__ int lastFlag;
  const int tid  = threadIdx.x;
  const int wave = tid >> 6;
  const int lane = tid & 63;
  const int cl   = lane & 15;
  const int q    = lane >> 4;

  // XCD-aware bijective swizzle: 2080 = 8 * 260.
  const int b = (blockIdx.x & 7) * 260 + (blockIdx.x >> 3);

  // linear tile -> (rt, ct) with rt <= ct over 64x64 tile grid
  int rt = (int)((129.0f - sqrtf(16641.0f - 8.0f * (float)b)) * 0.5f);
  if (rt > 63) rt = 63;
  if (rt < 0) rt = 0;
  while (rt > 0 && 64 * rt - rt * (rt - 1) / 2 > b) rt--;
  while (64 * (rt + 1) - (rt + 1) * rt / 2 <= b) rt++;
  const int ct = rt + (b - (64 * rt - rt * (rt - 1) / 2));

  const int wr = (wave >> 1) * 64;   // wave's row offset in tile
  const int wc = (wave & 1) * 64;    // wave's col offset in tile

  // staging: thread owns granules tid, tid+256 of each 128x64B tile
  const int r0  = tid >> 2;                              // 0..63
  const int sg  = ((tid & 3) ^ ((r0 >> 1) & 3)) * 16;    // pre-swizzled granule byte
  const unsigned char* gA0 = Zn + (size_t)(rt * 128 + r0) * DIM + sg;
  const unsigned char* gB0 = Zn + (size_t)(ct * 128 + r0) * DIM + sg;

  f32x4 acc[4][4] = {};
  const int xk2 = (cl >> 1) & 3;        // read-side key (row bits from cl)
  const int gofs = ((q ^ xk2) << 4);    // granule byte offset within row

#define STAGE(d, it)                                                        \
  {                                                                         \
    char* _b = smem + (d) * 16384 + wave * 1024;                            \
    const int _ko = (it) * BKB;                                             \
    ASYNC_COPY16(gA0 + _ko,            _b);                                 \
    ASYNC_COPY16(gA0 + _ko + 64 * DIM, _b + 4096);                          \
    ASYNC_COPY16(gB0 + _ko,            _b + 8192);                          \
    ASYNC_COPY16(gB0 + _ko + 64 * DIM, _b + 12288);                         \
  }

  STAGE(0, 0);
  STAGE(1, 1);
#pragma unroll
  for (int ks = 0; ks < NKS; ks++) {
    const int cur = ks % 3;
    // wait for buf[cur]'s 4 loads (issued 2 iterations ago); the newest 4
    // (next buffer) stay in flight. Full drain only on the last iteration.
    if (ks + 1 < NKS) { VMCNT(4); } else { VMCNT(0); }
    __builtin_amdgcn_s_barrier();
    asm volatile("" ::: "memory");
    if (ks + 2 < NKS) STAGE((ks + 2) % 3, ks + 2);

    const char* sA = smem + cur * 16384;
    const char* sB = sA + 8192;
    fp8x8 af[2][4], bfr[2][4];
#pragma unroll
    for (int i = 0; i < 4; i++) {
      fp8x8x2 av = *reinterpret_cast<const fp8x8x2*>(sA + (wr + i * 16 + cl) * 64 + gofs);
      af[0][i] = av[0];
      af[1][i] = av[1];
    }
#pragma unroll
    for (int j = 0; j < 4; j++) {
      fp8x8x2 bv = *reinterpret_cast<const fp8x8x2*>(sB + (wc + j * 16 + cl) * 64 + gofs);
      bfr[0][j] = bv[0];
      bfr[1][j] = bv[1];
    }
#pragma unroll
    for (int ksub = 0; ksub < 2; ksub++)
#pragma unroll
      for (int i = 0; i < 4; i++)
#pragma unroll
        for (int j = 0; j < 4; j++)
          acc[i][j] = __builtin_amdgcn_mfma_f32_16x16x32_fp8_fp8(af[ksub][i], bfr[ksub][j],
                                                                 acc[i][j], 0, 0, 0);
  }
#undef STAGE

  // Epilogue: e = exp(s - C) with diagonal masked.
  // C-frag layout: col = cl, row = q*4 + r (dtype-independent on gfx950).
  const bool diagw = (rt == ct) && (wr == wc);
  float psum[4][4];
#pragma unroll
  for (int i = 0; i < 4; i++)
#pragma unroll
    for (int r = 0; r < 4; r++) psum[i][r] = 0.f;
  float colp[4] = {0.f, 0.f, 0.f, 0.f};

#pragma unroll
  for (int i = 0; i < 4; i++)
#pragma unroll
    for (int j = 0; j < 4; j++)
#pragma unroll
      for (int r = 0; r < 4; r++) {
        float e = exp2f(fmaf(acc[i][j][r], LOG2E, -C_LOG2E));
        if (diagw && (i == j) && (cl == q * 4 + r)) e = 0.f;
        psum[i][r] += e;
        colp[j] += e;
      }

  // row sums -> rt rows (reduce across cols: cl lanes)
#pragma unroll
  for (int i = 0; i < 4; i++)
#pragma unroll
    for (int r = 0; r < 4; r++) {
      float v = psum[i][r];
      v += __shfl_xor(v, 1, 64);
      v += __shfl_xor(v, 2, 64);
      v += __shfl_xor(v, 4, 64);
      v += __shfl_xor(v, 8, 64);
      if (cl == 0) atomicAdd(&rowsum[rt * 128 + wr + i * 16 + q * 4 + r], v);
    }

  // col sums -> ct rows (reduce across rows: q lanes), off-diagonal tiles only
  if (rt != ct) {
#pragma unroll
    for (int j = 0; j < 4; j++) {
      float v = colp[j];
      v += __shfl_xor(v, 16, 64);
      v += __shfl_xor(v, 32, 64);
      if (q == 0) atomicAdd(&rowsum[ct * 128 + wc + j * 16 + cl], v);
    }
  }

  // -------- last-block finalize (replaces the k_final launch) --------
  __threadfence();                 // make this block's rowsum atomics visible
  __syncthreads();
  if (tid == 0)
    lastFlag = (atomicAdd(done, 1) == NBLK - 1);
  __syncthreads();
  if (lastFlag) {
    float s = 0.f;
#pragma unroll
    for (int it = 0; it < TWO_N / 256; it++) {
      const int row = it * 256 + tid;
      float v = __hip_atomic_load(&rowsum[row], __ATOMIC_RELAXED,
                                  __HIP_MEMORY_SCOPE_AGENT);
      v = logf(v);
      if (row < N_ROWS) v -= 2.f * posbuf[row];
      s += v;
    }
#pragma unroll
    for (int off = 32; off > 0; off >>= 1) s += __shfl_down(s, off, 64);
    if (lane == 0) red[wave] = s;
    __syncthreads();
    if (tid == 0)
      out[0] = (red[0] + red[1] + red[2] + red[3]) / (float)TWO_N + INV_T;
  }
}

extern "C" void kernel_launch(void* const* d_in, const int* in_sizes, int n_in,
                              void* d_out, int out_size, void* d_ws, size_t ws_size,
                              hipStream_t stream) {
  const float* z1 = (const float*)d_in[0];
  const float* z2 = (const float*)d_in[1];
  float* out = (float*)d_out;
  char* ws = (char*)d_ws;

  unsigned char* zn = (unsigned char*)ws;                 // 8192*512*1 = 4194304 B
  float* rowsum = (float*)(ws + 4194304);                 // 8192*4 = 32768 B
  float* posbuf = (float*)(ws + 4227072);                 // 4096*4 = 16384 B
  int* done     = (int*)(ws + 4243456);                   // 4 B

  k_prep<<<1024, 256, 0, stream>>>(z1, z2, zn, posbuf, rowsum, done);
  k_lse<<<NBLK, 256, 0, stream>>>(zn, rowsum, posbuf, done, out);
}

// Round 13
// 121.634 us; speedup vs baseline: 1.8920x; 1.8920x over previous
//
#include <hip/hip_runtime.h>
#include <hip/hip_bf16.h>
#include <hip/hip_fp8.h>

#define N_ROWS 4096
#define TWO_N 8192
#define DIM 512                             // elements per row; fp8 row = 512 B
#define BKB 64                              // K bytes per iter in fp8
#define NKS (DIM / BKB)                     // 8 K-steps
#define NBLK 2080
#define INV_T 14.285714285714286f           // 1/0.07
#define LOG2E 1.4426950408889634f
#define C_LOG2E 20.60992915555662f          // (1/0.07)*log2(e)
#define INV_SQRT_T 3.7796447300922722f      // 1/sqrt(0.07)

typedef float f32x4 __attribute__((ext_vector_type(4)));
typedef long fp8x8;                          // 8 fp8 = one 64-bit MFMA operand
typedef long fp8x8x2 __attribute__((ext_vector_type(2)));   // b128 = 2 operands

#define ASYNC_COPY16(gp, lp)                                                     \
  __builtin_amdgcn_global_load_lds((const __attribute__((address_space(1))) void*)(gp), \
                                   (__attribute__((address_space(3))) void*)(lp), 16, 0, 0)

#define VMCNT(n) asm volatile("s_waitcnt vmcnt(" #n ")" ::: "memory")

// Wave-per-row prep: float4 loads, butterfly shuffle reduce, fp8 e4m3 pack.
// Zn is stored K-PERMUTED: within each 64B k-block, 8B slot l (k=l*8..l*8+7)
// is placed at position (l&3)*16 + (l>>2)*8 (order [0,4,1,5,2,6,3,7]) so the
// two operands MFMA-lane q needs (slots q, q+4) are ADJACENT -> one b128
// read per fragment pair in k_lse. Exact: a global k-permutation of the
// Gram matrix inner dim, applied identically to A and B.
// posbuf (the subtracted positive) stays FP32-exact. Also zeroes rowsum+done.
__global__ __launch_bounds__(256) void k_prep(const float* __restrict__ z1,
                                              const float* __restrict__ z2,
                                              unsigned char* __restrict__ zn,
                                              float* __restrict__ posbuf,
                                              float* __restrict__ rowsum,
                                              int* __restrict__ done) {
  const int t = threadIdx.x;
  const int wv = t >> 6, lane = t & 63;
  const int r = blockIdx.x * 4 + wv;
  if (blockIdx.x < 32) rowsum[blockIdx.x * 256 + t] = 0.f;   // 32*256 = 8192
  if (blockIdx.x == 32 && t == 0) *done = 0;

  const float4* p1 = reinterpret_cast<const float4*>(z1 + (size_t)r * DIM) + (lane << 1);
  const float4* p2 = reinterpret_cast<const float4*>(z2 + (size_t)r * DIM) + (lane << 1);
  float4 a0 = p1[0], a1 = p1[1];
  float4 b0 = p2[0], b1 = p2[1];

  float s1 = a0.x * a0.x + a0.y * a0.y + a0.z * a0.z + a0.w * a0.w
           + a1.x * a1.x + a1.y * a1.y + a1.z * a1.z + a1.w * a1.w;
  float s2 = b0.x * b0.x + b0.y * b0.y + b0.z * b0.z + b0.w * b0.w
           + b1.x * b1.x + b1.y * b1.y + b1.z * b1.z + b1.w * b1.w;
  float sd = a0.x * b0.x + a0.y * b0.y + a0.z * b0.z + a0.w * b0.w
           + a1.x * b1.x + a1.y * b1.y + a1.z * b1.z + a1.w * b1.w;
#pragma unroll
  for (int off = 1; off < 64; off <<= 1) {
    s1 += __shfl_xor(s1, off, 64);
    s2 += __shfl_xor(s2, off, 64);
    sd += __shfl_xor(sd, off, 64);
  }
  const float sc1 = INV_SQRT_T / fmaxf(sqrtf(s1), 1e-8f);
  const float sc2 = INV_SQRT_T / fmaxf(sqrtf(s2), 1e-8f);

  float va[8] = {a0.x, a0.y, a0.z, a0.w, a1.x, a1.y, a1.z, a1.w};
  float vb[8] = {b0.x, b0.y, b0.z, b0.w, b1.x, b1.y, b1.z, b1.w};
  unsigned long long pa = 0, pb = 0;
#pragma unroll
  for (int d = 0; d < 8; d++) {
    __hip_fp8_e4m3 qa(va[d] * sc1);
    __hip_fp8_e4m3 qb(vb[d] * sc2);
    pa |= (unsigned long long)qa.__x << (8 * d);
    pb |= (unsigned long long)qb.__x << (8 * d);
  }
  // lane covers k = lane*8..+7 -> block = lane>>3, slot l = lane&7,
  // permuted position = block*64 + (l&3)*16 + (l>>2)*8
  const int pofs = (lane >> 3) * 64 + (lane & 3) * 16 + ((lane >> 2) & 1) * 8;
  *reinterpret_cast<unsigned long long*>(zn + (size_t)r * DIM + pofs) = pa;
  *reinterpret_cast<unsigned long long*>(zn + (size_t)(r + N_ROWS) * DIM + pofs) = pb;

  if (lane == 0) posbuf[r] = sd * sc1 * sc2;   // fp32-exact cos(z1_r,z2_r)/T
}

// ---------------------------------------------------------------------------
// Flash-LSE GEMM over upper-triangle 128x128 tiles -- FP8 e4m3, b128 reads.
// CHAMPION BODY = r10 verbatim (57.4us): 3 LDS buffers 48KB -> 3 blocks/CU,
// counted VMCNT(4) (2-iter slack, full drain only at tail), raw s_barrier,
// stage-after-barrier, XCD-bijective block swizzle, K-permuted global layout
// + granule XOR swizzle (measured 0 bank conflicts), 8 ds_read_b128 + 32
// MFMA per iter.
//
// r12 post-mortem: the ticket-fold itself was fine (absmax 0.0) but
// __threadfence() executed by ALL threads of ALL blocks = an L2
// writeback/maintenance storm (+114us, MfmaUtil 22->7.9 = exact 3x
// dilution). THE FENCE IS UNNECESSARY: __syncthreads() compiles to
// s_waitcnt vmcnt(0)+s_barrier, and vmcnt retirement of global_atomic_add
// means the atomic has PERFORMED at the device-coherent point (default
// atomicAdd is device-scope, m20). So: atomics -> syncthreads (drain) ->
// ticket atomicAdd -> last block reads rowsum via AGENT-scope atomic loads
// (bypass L1/L2; r12-verified reader). Zero cache-maintenance ops.
// ---------------------------------------------------------------------------
__global__ __launch_bounds__(256, 3) void k_lse(const unsigned char* __restrict__ Zn,
                                                float* __restrict__ rowsum,
                                                const float* __restrict__ posbuf,
                                                int* __restrict__ done,
                                                float* __restrict__ out) {
  __shared__ char smem[49152] __attribute__((aligned(16)));
  __shared__ float red[4];
  __shared__ int lastFlag;
  const int tid  = threadIdx.x;
  const int wave = tid >> 6;
  const int lane = tid & 63;
  const int cl   = lane & 15;
  const int q    = lane >> 4;

  // XCD-aware bijective swizzle: 2080 = 8 * 260.
  const int b = (blockIdx.x & 7) * 260 + (blockIdx.x >> 3);

  // linear tile -> (rt, ct) with rt <= ct over 64x64 tile grid
  int rt = (int)((129.0f - sqrtf(16641.0f - 8.0f * (float)b)) * 0.5f);
  if (rt > 63) rt = 63;
  if (rt < 0) rt = 0;
  while (rt > 0 && 64 * rt - rt * (rt - 1) / 2 > b) rt--;
  while (64 * (rt + 1) - (rt + 1) * rt / 2 <= b) rt++;
  const int ct = rt + (b - (64 * rt - rt * (rt - 1) / 2));

  const int wr = (wave >> 1) * 64;   // wave's row offset in tile
  const int wc = (wave & 1) * 64;    // wave's col offset in tile

  // staging: thread owns granules tid, tid+256 of each 128x64B tile
  const int r0  = tid >> 2;                              // 0..63
  const int sg  = ((tid & 3) ^ ((r0 >> 1) & 3)) * 16;    // pre-swizzled granule byte
  const unsigned char* gA0 = Zn + (size_t)(rt * 128 + r0) * DIM + sg;
  const unsigned char* gB0 = Zn + (size_t)(ct * 128 + r0) * DIM + sg;

  f32x4 acc[4][4] = {};
  const int xk2 = (cl >> 1) & 3;        // read-side key (row bits from cl)
  const int gofs = ((q ^ xk2) << 4);    // granule byte offset within row

#define STAGE(d, it)                                                        \
  {                                                                         \
    char* _b = smem + (d) * 16384 + wave * 1024;                            \
    const int _ko = (it) * BKB;                                             \
    ASYNC_COPY16(gA0 + _ko,            _b);                                 \
    ASYNC_COPY16(gA0 + _ko + 64 * DIM, _b + 4096);                          \
    ASYNC_COPY16(gB0 + _ko,            _b + 8192);                          \
    ASYNC_COPY16(gB0 + _ko + 64 * DIM, _b + 12288);                         \
  }

  STAGE(0, 0);
  STAGE(1, 1);
#pragma unroll
  for (int ks = 0; ks < NKS; ks++) {
    const int cur = ks % 3;
    // wait for buf[cur]'s 4 loads (issued 2 iterations ago); the newest 4
    // (next buffer) stay in flight. Full drain only on the last iteration.
    if (ks + 1 < NKS) { VMCNT(4); } else { VMCNT(0); }
    __builtin_amdgcn_s_barrier();
    asm volatile("" ::: "memory");
    if (ks + 2 < NKS) STAGE((ks + 2) % 3, ks + 2);

    const char* sA = smem + cur * 16384;
    const char* sB = sA + 8192;
    fp8x8 af[2][4], bfr[2][4];
#pragma unroll
    for (int i = 0; i < 4; i++) {
      fp8x8x2 av = *reinterpret_cast<const fp8x8x2*>(sA + (wr + i * 16 + cl) * 64 + gofs);
      af[0][i] = av[0];
      af[1][i] = av[1];
    }
#pragma unroll
    for (int j = 0; j < 4; j++) {
      fp8x8x2 bv = *reinterpret_cast<const fp8x8x2*>(sB + (wc + j * 16 + cl) * 64 + gofs);
      bfr[0][j] = bv[0];
      bfr[1][j] = bv[1];
    }
#pragma unroll
    for (int ksub = 0; ksub < 2; ksub++)
#pragma unroll
      for (int i = 0; i < 4; i++)
#pragma unroll
        for (int j = 0; j < 4; j++)
          acc[i][j] = __builtin_amdgcn_mfma_f32_16x16x32_fp8_fp8(af[ksub][i], bfr[ksub][j],
                                                                 acc[i][j], 0, 0, 0);
  }
#undef STAGE

  // Epilogue: e = exp(s - C) with diagonal masked.
  // C-frag layout: col = cl, row = q*4 + r (dtype-independent on gfx950).
  const bool diagw = (rt == ct) && (wr == wc);
  float psum[4][4];
#pragma unroll
  for (int i = 0; i < 4; i++)
#pragma unroll
    for (int r = 0; r < 4; r++) psum[i][r] = 0.f;
  float colp[4] = {0.f, 0.f, 0.f, 0.f};

#pragma unroll
  for (int i = 0; i < 4; i++)
#pragma unroll
    for (int j = 0; j < 4; j++)
#pragma unroll
      for (int r = 0; r < 4; r++) {
        float e = exp2f(fmaf(acc[i][j][r], LOG2E, -C_LOG2E));
        if (diagw && (i == j) && (cl == q * 4 + r)) e = 0.f;
        psum[i][r] += e;
        colp[j] += e;
      }

  // row sums -> rt rows (reduce across cols: cl lanes)
#pragma unroll
  for (int i = 0; i < 4; i++)
#pragma unroll
    for (int r = 0; r < 4; r++) {
      float v = psum[i][r];
      v += __shfl_xor(v, 1, 64);
      v += __shfl_xor(v, 2, 64);
      v += __shfl_xor(v, 4, 64);
      v += __shfl_xor(v, 8, 64);
      if (cl == 0) atomicAdd(&rowsum[rt * 128 + wr + i * 16 + q * 4 + r], v);
    }

  // col sums -> ct rows (reduce across rows: q lanes), off-diagonal tiles only
  if (rt != ct) {
#pragma unroll
    for (int j = 0; j < 4; j++) {
      float v = colp[j];
      v += __shfl_xor(v, 16, 64);
      v += __shfl_xor(v, 32, 64);
      if (q == 0) atomicAdd(&rowsum[ct * 128 + wc + j * 16 + cl], v);
    }
  }

  // -------- last-block finalize (NO threadfence -- see header) --------
  __syncthreads();                 // implicit vmcnt(0): our atomics performed
  if (tid == 0)
    lastFlag = (atomicAdd(done, 1) == NBLK - 1);
  __syncthreads();
  if (lastFlag) {
    float s = 0.f;
#pragma unroll
    for (int it = 0; it < TWO_N / 256; it++) {
      const int row = it * 256 + tid;
      float v = __hip_atomic_load(&rowsum[row], __ATOMIC_RELAXED,
                                  __HIP_MEMORY_SCOPE_AGENT);
      v = logf(v);
      if (row < N_ROWS) v -= 2.f * posbuf[row];
      s += v;
    }
#pragma unroll
    for (int off = 32; off > 0; off >>= 1) s += __shfl_down(s, off, 64);
    if (lane == 0) red[wave] = s;
    __syncthreads();
    if (tid == 0)
      out[0] = (red[0] + red[1] + red[2] + red[3]) / (float)TWO_N + INV_T;
  }
}

extern "C" void kernel_launch(void* const* d_in, const int* in_sizes, int n_in,
                              void* d_out, int out_size, void* d_ws, size_t ws_size,
                              hipStream_t stream) {
  const float* z1 = (const float*)d_in[0];
  const float* z2 = (const float*)d_in[1];
  float* out = (float*)d_out;
  char* ws = (char*)d_ws;

  unsigned char* zn = (unsigned char*)ws;                 // 8192*512*1 = 4194304 B
  float* rowsum = (float*)(ws + 4194304);                 // 8192*4 = 32768 B
  float* posbuf = (float*)(ws + 4227072);                 // 4096*4 = 16384 B
  int* done     = (int*)(ws + 4243456);                   // 4 B

  k_prep<<<1024, 256, 0, stream>>>(z1, z2, zn, posbuf, rowsum, done);
  k_lse<<<NBLK, 256, 0, stream>>>(zn, rowsum, posbuf, done, out);
}

// Round 14
// 116.148 us; speedup vs baseline: 1.9813x; 1.0472x over previous
//
#include <hip/hip_runtime.h>
#include <hip/hip_bf16.h>
#include <hip/hip_fp8.h>

#define N_ROWS 4096
#define TWO_N 8192
#define DIM 512                             // elements per row; fp8 row = 512 B
#define BKB 64                              // K bytes per iter in fp8
#define NKS (DIM / BKB)                     // 8 K-steps
#define INV_T 14.285714285714286f           // 1/0.07
#define LOG2E 1.4426950408889634f
#define C_LOG2E 20.60992915555662f          // (1/0.07)*log2(e)
#define INV_SQRT_T 3.7796447300922722f      // 1/sqrt(0.07)

typedef float f32x4 __attribute__((ext_vector_type(4)));
typedef long fp8x8;                          // 8 fp8 = one 64-bit MFMA operand
typedef long fp8x8x2 __attribute__((ext_vector_type(2)));   // b128 = 2 operands

#define ASYNC_COPY16(gp, lp)                                                     \
  __builtin_amdgcn_global_load_lds((const __attribute__((address_space(1))) void*)(gp), \
                                   (__attribute__((address_space(3))) void*)(lp), 16, 0, 0)

#define VMCNT(n) asm volatile("s_waitcnt vmcnt(" #n ")" ::: "memory")

// Wave-per-row prep: float4 loads, butterfly shuffle reduce, fp8 e4m3 pack.
// Zn is stored K-PERMUTED: within each 64B k-block, 8B slot l (k=l*8..l*8+7)
// is placed at position (l&3)*16 + (l>>2)*8 (order [0,4,1,5,2,6,3,7]) so the
// two operands MFMA-lane q needs (slots q, q+4) are ADJACENT -> one b128
// read per fragment pair in k_lse. Exact: a global k-permutation of the
// Gram matrix inner dim, applied identically to A and B.
// posbuf (the subtracted positive) stays FP32-exact. Also zeroes rowsum.
__global__ __launch_bounds__(256) void k_prep(const float* __restrict__ z1,
                                              const float* __restrict__ z2,
                                              unsigned char* __restrict__ zn,
                                              float* __restrict__ posbuf,
                                              float* __restrict__ rowsum) {
  const int t = threadIdx.x;
  const int wv = t >> 6, lane = t & 63;
  const int r = blockIdx.x * 4 + wv;
  if (blockIdx.x < 32) rowsum[blockIdx.x * 256 + t] = 0.f;   // 32*256 = 8192

  const float4* p1 = reinterpret_cast<const float4*>(z1 + (size_t)r * DIM) + (lane << 1);
  const float4* p2 = reinterpret_cast<const float4*>(z2 + (size_t)r * DIM) + (lane << 1);
  float4 a0 = p1[0], a1 = p1[1];
  float4 b0 = p2[0], b1 = p2[1];

  float s1 = a0.x * a0.x + a0.y * a0.y + a0.z * a0.z + a0.w * a0.w
           + a1.x * a1.x + a1.y * a1.y + a1.z * a1.z + a1.w * a1.w;
  float s2 = b0.x * b0.x + b0.y * b0.y + b0.z * b0.z + b0.w * b0.w
           + b1.x * b1.x + b1.y * b1.y + b1.z * b1.z + b1.w * b1.w;
  float sd = a0.x * b0.x + a0.y * b0.y + a0.z * b0.z + a0.w * b0.w
           + a1.x * b1.x + a1.y * b1.y + a1.z * b1.z + a1.w * b1.w;
#pragma unroll
  for (int off = 1; off < 64; off <<= 1) {
    s1 += __shfl_xor(s1, off, 64);
    s2 += __shfl_xor(s2, off, 64);
    sd += __shfl_xor(sd, off, 64);
  }
  const float sc1 = INV_SQRT_T / fmaxf(sqrtf(s1), 1e-8f);
  const float sc2 = INV_SQRT_T / fmaxf(sqrtf(s2), 1e-8f);

  float va[8] = {a0.x, a0.y, a0.z, a0.w, a1.x, a1.y, a1.z, a1.w};
  float vb[8] = {b0.x, b0.y, b0.z, b0.w, b1.x, b1.y, b1.z, b1.w};
  unsigned long long pa = 0, pb = 0;
#pragma unroll
  for (int d = 0; d < 8; d++) {
    __hip_fp8_e4m3 qa(va[d] * sc1);
    __hip_fp8_e4m3 qb(vb[d] * sc2);
    pa |= (unsigned long long)qa.__x << (8 * d);
    pb |= (unsigned long long)qb.__x << (8 * d);
  }
  // lane covers k = lane*8..+7 -> block = lane>>3, slot l = lane&7,
  // permuted position = block*64 + (l&3)*16 + (l>>2)*8
  const int pofs = (lane >> 3) * 64 + (lane & 3) * 16 + ((lane >> 2) & 1) * 8;
  *reinterpret_cast<unsigned long long*>(zn + (size_t)r * DIM + pofs) = pa;
  *reinterpret_cast<unsigned long long*>(zn + (size_t)(r + N_ROWS) * DIM + pofs) = pb;

  if (lane == 0) posbuf[r] = sd * sc1 * sc2;   // fp32-exact cos(z1_r,z2_r)/T
}

// ---------------------------------------------------------------------------
// Flash-LSE GEMM over upper-triangle 128x128 tiles -- FP8 e4m3, b128 reads.
// r13 post-mortem: the ticket-fold gained nothing (boundaries are cheap in
// this graph-captured harness) -- retired; back to r10's 3-kernel structure.
//
// THIS ROUND'S ONE CHANGE vs r10 (57.4us): 2 LDS buffers instead of 3
// (32 KB) -> 4 BLOCKS/CU (16 waves). Cross-block overlap is the only lever
// that has ever moved this kernel (3 blk/CU beat 2 blk/CU in r3/r4/r7/r11);
// 4 blk/CU was only ever tried with broken wait discipline (r1: full drain
// of 300cy-old loads; r5: 400cy slack). Here, with fp8's ~2100cy iteration:
//   iter ks: VMCNT(0)   -- own stage(ks) landed (issued mid-iter ks-1,
//                          ~1500-2000cy ago >> ~800cy L3 latency)
//            s_barrier  -- all waves' stages visible; iter ks-1 reads done
//            8x ds_read_b128 from buf[ks&1]
//            STAGE(ks+1) -> buf[(ks+1)&1]  (read at ks-1; safe post-barrier)
//            32x MFMA
// K-permuted global layout + granule XOR swizzle identical to r10
// (measured 0 bank conflicts). XCD-bijective block swizzle (2080 = 8*260).
// ---------------------------------------------------------------------------
__global__ __launch_bounds__(256, 4) void k_lse(const unsigned char* __restrict__ Zn,
                                                float* __restrict__ rowsum) {
  __shared__ char smem[32768] __attribute__((aligned(16)));
  const int tid  = threadIdx.x;
  const int wave = tid >> 6;
  const int lane = tid & 63;
  const int cl   = lane & 15;
  const int q    = lane >> 4;

  // XCD-aware bijective swizzle: 2080 = 8 * 260.
  const int b = (blockIdx.x & 7) * 260 + (blockIdx.x >> 3);

  // linear tile -> (rt, ct) with rt <= ct over 64x64 tile grid
  int rt = (int)((129.0f - sqrtf(16641.0f - 8.0f * (float)b)) * 0.5f);
  if (rt > 63) rt = 63;
  if (rt < 0) rt = 0;
  while (rt > 0 && 64 * rt - rt * (rt - 1) / 2 > b) rt--;
  while (64 * (rt + 1) - (rt + 1) * rt / 2 <= b) rt++;
  const int ct = rt + (b - (64 * rt - rt * (rt - 1) / 2));

  const int wr = (wave >> 1) * 64;   // wave's row offset in tile
  const int wc = (wave & 1) * 64;    // wave's col offset in tile

  // staging: thread owns granules tid, tid+256 of each 128x64B tile
  const int r0  = tid >> 2;                              // 0..63
  const int sg  = ((tid & 3) ^ ((r0 >> 1) & 3)) * 16;    // pre-swizzled granule byte
  const unsigned char* gA0 = Zn + (size_t)(rt * 128 + r0) * DIM + sg;
  const unsigned char* gB0 = Zn + (size_t)(ct * 128 + r0) * DIM + sg;

  f32x4 acc[4][4] = {};
  const int xk2 = (cl >> 1) & 3;        // read-side key (row bits from cl)
  const int gofs = ((q ^ xk2) << 4);    // granule byte offset within row

#define STAGE(d, it)                                                        \
  {                                                                         \
    char* _b = smem + (d) * 16384 + wave * 1024;                            \
    const int _ko = (it) * BKB;                                             \
    ASYNC_COPY16(gA0 + _ko,            _b);                                 \
    ASYNC_COPY16(gA0 + _ko + 64 * DIM, _b + 4096);                          \
    ASYNC_COPY16(gB0 + _ko,            _b + 8192);                          \
    ASYNC_COPY16(gB0 + _ko + 64 * DIM, _b + 12288);                         \
  }

  STAGE(0, 0);
#pragma unroll
  for (int ks = 0; ks < NKS; ks++) {
    // own stage(ks) landed (issued ~a full iteration ago, mid-iter ks-1)
    VMCNT(0);
    __builtin_amdgcn_s_barrier();
    asm volatile("" ::: "memory");

    const char* sA = smem + (ks & 1) * 16384;
    const char* sB = sA + 8192;
    fp8x8 af[2][4], bfr[2][4];
#pragma unroll
    for (int i = 0; i < 4; i++) {
      fp8x8x2 av = *reinterpret_cast<const fp8x8x2*>(sA + (wr + i * 16 + cl) * 64 + gofs);
      af[0][i] = av[0];
      af[1][i] = av[1];
    }
#pragma unroll
    for (int j = 0; j < 4; j++) {
      fp8x8x2 bv = *reinterpret_cast<const fp8x8x2*>(sB + (wc + j * 16 + cl) * 64 + gofs);
      bfr[0][j] = bv[0];
      bfr[1][j] = bv[1];
    }
    // issue next stage under this iter's MFMA cluster; drained at next
    // iter's VMCNT(0). Target buffer was read at iter ks-1 (safe: barrier).
    if (ks + 1 < NKS) STAGE((ks + 1) & 1, ks + 1);

#pragma unroll
    for (int ksub = 0; ksub < 2; ksub++)
#pragma unroll
      for (int i = 0; i < 4; i++)
#pragma unroll
        for (int j = 0; j < 4; j++)
          acc[i][j] = __builtin_amdgcn_mfma_f32_16x16x32_fp8_fp8(af[ksub][i], bfr[ksub][j],
                                                                 acc[i][j], 0, 0, 0);
  }
#undef STAGE

  // Epilogue: e = exp(s - C) with diagonal masked.
  // C-frag layout: col = cl, row = q*4 + r (dtype-independent on gfx950).
  const bool diagw = (rt == ct) && (wr == wc);
  float psum[4][4];
#pragma unroll
  for (int i = 0; i < 4; i++)
#pragma unroll
    for (int r = 0; r < 4; r++) psum[i][r] = 0.f;
  float colp[4] = {0.f, 0.f, 0.f, 0.f};

#pragma unroll
  for (int i = 0; i < 4; i++)
#pragma unroll
    for (int j = 0; j < 4; j++)
#pragma unroll
      for (int r = 0; r < 4; r++) {
        float e = exp2f(fmaf(acc[i][j][r], LOG2E, -C_LOG2E));
        if (diagw && (i == j) && (cl == q * 4 + r)) e = 0.f;
        psum[i][r] += e;
        colp[j] += e;
      }

  // row sums -> rt rows (reduce across cols: cl lanes)
#pragma unroll
  for (int i = 0; i < 4; i++)
#pragma unroll
    for (int r = 0; r < 4; r++) {
      float v = psum[i][r];
      v += __shfl_xor(v, 1, 64);
      v += __shfl_xor(v, 2, 64);
      v += __shfl_xor(v, 4, 64);
      v += __shfl_xor(v, 8, 64);
      if (cl == 0) atomicAdd(&rowsum[rt * 128 + wr + i * 16 + q * 4 + r], v);
    }

  // col sums -> ct rows (reduce across rows: q lanes), off-diagonal tiles only
  if (rt != ct) {
#pragma unroll
    for (int j = 0; j < 4; j++) {
      float v = colp[j];
      v += __shfl_xor(v, 16, 64);
      v += __shfl_xor(v, 32, 64);
      if (q == 0) atomicAdd(&rowsum[ct * 128 + wc + j * 16 + cl], v);
    }
  }
}

// Single-block finalize: 1024 threads, each handles 8 rows.
__global__ void k_final(const float* __restrict__ rowsum, const float* __restrict__ posbuf,
                        float* __restrict__ out) {
  __shared__ float red[16];
  const int t = threadIdx.x;   // 1024 threads
  float s = 0.f;
#pragma unroll
  for (int it = 0; it < TWO_N / 1024; it++) {
    const int row = it * 1024 + t;
    float v = logf(rowsum[row]);
    if (row < N_ROWS) v -= 2.f * posbuf[row];
    s += v;
  }
#pragma unroll
  for (int off = 32; off > 0; off >>= 1) s += __shfl_down(s, off, 64);
  if ((t & 63) == 0) red[t >> 6] = s;
  __syncthreads();
  if (t == 0) {
    float tot = 0.f;
#pragma unroll
    for (int i = 0; i < 16; i++) tot += red[i];
    out[0] = tot / (float)TWO_N + INV_T;
  }
}

extern "C" void kernel_launch(void* const* d_in, const int* in_sizes, int n_in,
                              void* d_out, int out_size, void* d_ws, size_t ws_size,
                              hipStream_t stream) {
  const float* z1 = (const float*)d_in[0];
  const float* z2 = (const float*)d_in[1];
  float* out = (float*)d_out;
  char* ws = (char*)d_ws;

  unsigned char* zn = (unsigned char*)ws;                 // 8192*512*1 = 4194304 B
  float* rowsum = (float*)(ws + 4194304);                 // 8192*4 = 32768 B
  float* posbuf = (float*)(ws + 4227072);                 // 4096*4 = 16384 B

  k_prep<<<1024, 256, 0, stream>>>(z1, z2, zn, posbuf, rowsum);
  k_lse<<<2080, 256, 0, stream>>>(zn, rowsum);
  k_final<<<1, 1024, 0, stream>>>(rowsum, posbuf, out);
}

// Round 15
// 108.305 us; speedup vs baseline: 2.1248x; 1.0724x over previous
//
#include <hip/hip_runtime.h>
#include <hip/hip_bf16.h>
#include <hip/hip_fp8.h>

#define N_ROWS 4096
#define TWO_N 8192
#define DIM 512                             // elements per row; fp8 row = 512 B
#define BKB 64                              // K bytes per iter in fp8
#define NKS (DIM / BKB)                     // 8 K-steps
#define INV_T 14.285714285714286f           // 1/0.07
#define LOG2E 1.4426950408889634f
#define C_LOG2E 20.60992915555662f          // (1/0.07)*log2(e)
#define INV_SQRT_T 3.7796447300922722f      // 1/sqrt(0.07)

typedef float f32x4 __attribute__((ext_vector_type(4)));
typedef long fp8x8;                          // 8 fp8 = one 64-bit MFMA operand
typedef long fp8x8x2 __attribute__((ext_vector_type(2)));   // b128 = 2 operands

#define ASYNC_COPY16(gp, lp)                                                     \
  __builtin_amdgcn_global_load_lds((const __attribute__((address_space(1))) void*)(gp), \
                                   (__attribute__((address_space(3))) void*)(lp), 16, 0, 0)

#define VMCNT(n) asm volatile("s_waitcnt vmcnt(" #n ")" ::: "memory")

// Wave-per-row prep: float4 loads, butterfly shuffle reduce, fp8 e4m3 pack.
// Zn is stored K-PERMUTED: within each 64B k-block, 8B slot l (k=l*8..l*8+7)
// is placed at position (l&3)*16 + (l>>2)*8 (order [0,4,1,5,2,6,3,7]) so the
// two operands MFMA-lane q needs (slots q, q+4) are ADJACENT -> one b128
// read per fragment pair in k_lse. Exact: a global k-permutation of the
// Gram matrix inner dim, applied identically to A and B.
// posbuf (the subtracted positive) stays FP32-exact. Also zeroes rowsum.
__global__ __launch_bounds__(256) void k_prep(const float* __restrict__ z1,
                                              const float* __restrict__ z2,
                                              unsigned char* __restrict__ zn,
                                              float* __restrict__ posbuf,
                                              float* __restrict__ rowsum) {
  const int t = threadIdx.x;
  const int wv = t >> 6, lane = t & 63;
  const int r = blockIdx.x * 4 + wv;
  if (blockIdx.x < 32) rowsum[blockIdx.x * 256 + t] = 0.f;   // 32*256 = 8192

  const float4* p1 = reinterpret_cast<const float4*>(z1 + (size_t)r * DIM) + (lane << 1);
  const float4* p2 = reinterpret_cast<const float4*>(z2 + (size_t)r * DIM) + (lane << 1);
  float4 a0 = p1[0], a1 = p1[1];
  float4 b0 = p2[0], b1 = p2[1];

  float s1 = a0.x * a0.x + a0.y * a0.y + a0.z * a0.z + a0.w * a0.w
           + a1.x * a1.x + a1.y * a1.y + a1.z * a1.z + a1.w * a1.w;
  float s2 = b0.x * b0.x + b0.y * b0.y + b0.z * b0.z + b0.w * b0.w
           + b1.x * b1.x + b1.y * b1.y + b1.z * b1.z + b1.w * b1.w;
  float sd = a0.x * b0.x + a0.y * b0.y + a0.z * b0.z + a0.w * b0.w
           + a1.x * b1.x + a1.y * b1.y + a1.z * b1.z + a1.w * b1.w;
#pragma unroll
  for (int off = 1; off < 64; off <<= 1) {
    s1 += __shfl_xor(s1, off, 64);
    s2 += __shfl_xor(s2, off, 64);
    sd += __shfl_xor(sd, off, 64);
  }
  const float sc1 = INV_SQRT_T / fmaxf(sqrtf(s1), 1e-8f);
  const float sc2 = INV_SQRT_T / fmaxf(sqrtf(s2), 1e-8f);

  float va[8] = {a0.x, a0.y, a0.z, a0.w, a1.x, a1.y, a1.z, a1.w};
  float vb[8] = {b0.x, b0.y, b0.z, b0.w, b1.x, b1.y, b1.z, b1.w};
  unsigned long long pa = 0, pb = 0;
#pragma unroll
  for (int d = 0; d < 8; d++) {
    __hip_fp8_e4m3 qa(va[d] * sc1);
    __hip_fp8_e4m3 qb(vb[d] * sc2);
    pa |= (unsigned long long)qa.__x << (8 * d);
    pb |= (unsigned long long)qb.__x << (8 * d);
  }
  // lane covers k = lane*8..+7 -> block = lane>>3, slot l = lane&7,
  // permuted position = block*64 + (l&3)*16 + (l>>2)*8
  const int pofs = (lane >> 3) * 64 + (lane & 3) * 16 + ((lane >> 2) & 1) * 8;
  *reinterpret_cast<unsigned long long*>(zn + (size_t)r * DIM + pofs) = pa;
  *reinterpret_cast<unsigned long long*>(zn + (size_t)(r + N_ROWS) * DIM + pofs) = pb;

  if (lane == 0) posbuf[r] = sd * sc1 * sc2;   // fp32-exact cos(z1_r,z2_r)/T
}

// ---------------------------------------------------------------------------
// Flash-LSE GEMM over upper-triangle 128x128 tiles -- FP8 e4m3, b128 reads.
// BODY = r14 champion verbatim (56.2us): 2 LDS buffers 32KB -> 4 blocks/CU,
// per iter {VMCNT(0); s_barrier; 8x ds_read_b128; STAGE(ks+1) under MFMA;
// 32x MFMA}, K-permuted global layout + granule XOR swizzle (0 conflicts).
//
// r14 post-mortem: no pipe above 30% (LDS 25%, MFMA 23%, VALU 26%, HBM 5%)
// -> LATENCY-bound on the VMCNT(0): stage slack (~1 MFMA cluster) < load
// latency, and latency is mostly L3 because FETCH=12MB = 3x the 4MB input
// (row-strip tile order streams 16MB of B-panels through each 4MB L2).
//
// THIS ROUND'S ONE CHANGE: locality-aware SUPER-TILE ordering. The 64x64
// tile triangle is split into 8x8 super-tiles (36 of them; diagonal = 36
// tiles, off-diag = 64; total 2080). Tiles are enumerated super-tile-major,
// so the working set per super-tile is 8 A-panels + 8 B-panels = 1MB << 4MB
// L2, each panel L2-reused 8x (vs 1x). Consecutive g on one XCD share
// panels. Stage latency -> L2 (~250cy) < slack -> VMCNT stall shrinks.
// ---------------------------------------------------------------------------
__global__ __launch_bounds__(256, 4) void k_lse(const unsigned char* __restrict__ Zn,
                                                float* __restrict__ rowsum) {
  __shared__ char smem[32768] __attribute__((aligned(16)));
  const int tid  = threadIdx.x;
  const int wave = tid >> 6;
  const int lane = tid & 63;
  const int cl   = lane & 15;
  const int q    = lane >> 4;

  // XCD-aware bijective swizzle: 2080 = 8 * 260.
  const int g = (blockIdx.x & 7) * 260 + (blockIdx.x >> 3);

  // super-tile decode: walk 8x8 super-tiles (R<=C) row-major; sizes 36/64.
  int rem = g, R = 0, C = 0;
  for (;;) {
    const int sz = (C == R) ? 36 : 64;
    if (rem < sz) break;
    rem -= sz;
    C++;
    if (C == 8) { R++; C = R; }
  }
  int rt, ct;
  if (C == R) {
    // triangular local index (row-major incl diagonal; row lr has 8-lr tiles)
    int lr = 0;
    while (rem >= 8 - lr) { rem -= 8 - lr; lr++; }
    rt = R * 8 + lr;
    ct = C * 8 + lr + rem;
  } else {
    rt = R * 8 + (rem >> 3);
    ct = C * 8 + (rem & 7);
  }

  const int wr = (wave >> 1) * 64;   // wave's row offset in tile
  const int wc = (wave & 1) * 64;    // wave's col offset in tile

  // staging: thread owns granules tid, tid+256 of each 128x64B tile
  const int r0  = tid >> 2;                              // 0..63
  const int sg  = ((tid & 3) ^ ((r0 >> 1) & 3)) * 16;    // pre-swizzled granule byte
  const unsigned char* gA0 = Zn + (size_t)(rt * 128 + r0) * DIM + sg;
  const unsigned char* gB0 = Zn + (size_t)(ct * 128 + r0) * DIM + sg;

  f32x4 acc[4][4] = {};
  const int xk2 = (cl >> 1) & 3;        // read-side key (row bits from cl)
  const int gofs = ((q ^ xk2) << 4);    // granule byte offset within row

#define STAGE(d, it)                                                        \
  {                                                                         \
    char* _b = smem + (d) * 16384 + wave * 1024;                            \
    const int _ko = (it) * BKB;                                             \
    ASYNC_COPY16(gA0 + _ko,            _b);                                 \
    ASYNC_COPY16(gA0 + _ko + 64 * DIM, _b + 4096);                          \
    ASYNC_COPY16(gB0 + _ko,            _b + 8192);                          \
    ASYNC_COPY16(gB0 + _ko + 64 * DIM, _b + 12288);                         \
  }

  STAGE(0, 0);
#pragma unroll
  for (int ks = 0; ks < NKS; ks++) {
    // own stage(ks) landed (issued ~a full iteration ago, mid-iter ks-1)
    VMCNT(0);
    __builtin_amdgcn_s_barrier();
    asm volatile("" ::: "memory");

    const char* sA = smem + (ks & 1) * 16384;
    const char* sB = sA + 8192;
    fp8x8 af[2][4], bfr[2][4];
#pragma unroll
    for (int i = 0; i < 4; i++) {
      fp8x8x2 av = *reinterpret_cast<const fp8x8x2*>(sA + (wr + i * 16 + cl) * 64 + gofs);
      af[0][i] = av[0];
      af[1][i] = av[1];
    }
#pragma unroll
    for (int j = 0; j < 4; j++) {
      fp8x8x2 bv = *reinterpret_cast<const fp8x8x2*>(sB + (wc + j * 16 + cl) * 64 + gofs);
      bfr[0][j] = bv[0];
      bfr[1][j] = bv[1];
    }
    // issue next stage under this iter's MFMA cluster; drained at next
    // iter's VMCNT(0). Target buffer was read at iter ks-1 (safe: barrier).
    if (ks + 1 < NKS) STAGE((ks + 1) & 1, ks + 1);

#pragma unroll
    for (int ksub = 0; ksub < 2; ksub++)
#pragma unroll
      for (int i = 0; i < 4; i++)
#pragma unroll
        for (int j = 0; j < 4; j++)
          acc[i][j] = __builtin_amdgcn_mfma_f32_16x16x32_fp8_fp8(af[ksub][i], bfr[ksub][j],
                                                                 acc[i][j], 0, 0, 0);
  }
#undef STAGE

  // Epilogue: e = exp(s - C) with diagonal masked.
  // C-frag layout: col = cl, row = q*4 + r (dtype-independent on gfx950).
  const bool diagw = (rt == ct) && (wr == wc);
  float psum[4][4];
#pragma unroll
  for (int i = 0; i < 4; i++)
#pragma unroll
    for (int r = 0; r < 4; r++) psum[i][r] = 0.f;
  float colp[4] = {0.f, 0.f, 0.f, 0.f};

#pragma unroll
  for (int i = 0; i < 4; i++)
#pragma unroll
    for (int j = 0; j < 4; j++)
#pragma unroll
      for (int r = 0; r < 4; r++) {
        float e = exp2f(fmaf(acc[i][j][r], LOG2E, -C_LOG2E));
        if (diagw && (i == j) && (cl == q * 4 + r)) e = 0.f;
        psum[i][r] += e;
        colp[j] += e;
      }

  // row sums -> rt rows (reduce across cols: cl lanes)
#pragma unroll
  for (int i = 0; i < 4; i++)
#pragma unroll
    for (int r = 0; r < 4; r++) {
      float v = psum[i][r];
      v += __shfl_xor(v, 1, 64);
      v += __shfl_xor(v, 2, 64);
      v += __shfl_xor(v, 4, 64);
      v += __shfl_xor(v, 8, 64);
      if (cl == 0) atomicAdd(&rowsum[rt * 128 + wr + i * 16 + q * 4 + r], v);
    }

  // col sums -> ct rows (reduce across rows: q lanes), off-diagonal tiles only
  if (rt != ct) {
#pragma unroll
    for (int j = 0; j < 4; j++) {
      float v = colp[j];
      v += __shfl_xor(v, 16, 64);
      v += __shfl_xor(v, 32, 64);
      if (q == 0) atomicAdd(&rowsum[ct * 128 + wc + j * 16 + cl], v);
    }
  }
}

// Single-block finalize: 1024 threads, each handles 8 rows.
__global__ void k_final(const float* __restrict__ rowsum, const float* __restrict__ posbuf,
                        float* __restrict__ out) {
  __shared__ float red[16];
  const int t = threadIdx.x;   // 1024 threads
  float s = 0.f;
#pragma unroll
  for (int it = 0; it < TWO_N / 1024; it++) {
    const int row = it * 1024 + t;
    float v = logf(rowsum[row]);
    if (row < N_ROWS) v -= 2.f * posbuf[row];
    s += v;
  }
#pragma unroll
  for (int off = 32; off > 0; off >>= 1) s += __shfl_down(s, off, 64);
  if ((t & 63) == 0) red[t >> 6] = s;
  __syncthreads();
  if (t == 0) {
    float tot = 0.f;
#pragma unroll
    for (int i = 0; i < 16; i++) tot += red[i];
    out[0] = tot / (float)TWO_N + INV_T;
  }
}

extern "C" void kernel_launch(void* const* d_in, const int* in_sizes, int n_in,
                              void* d_out, int out_size, void* d_ws, size_t ws_size,
                              hipStream_t stream) {
  const float* z1 = (const float*)d_in[0];
  const float* z2 = (const float*)d_in[1];
  float* out = (float*)d_out;
  char* ws = (char*)d_ws;

  unsigned char* zn = (unsigned char*)ws;                 // 8192*512*1 = 4194304 B
  float* rowsum = (float*)(ws + 4194304);                 // 8192*4 = 32768 B
  float* posbuf = (float*)(ws + 4227072);                 // 4096*4 = 16384 B

  k_prep<<<1024, 256, 0, stream>>>(z1, z2, zn, posbuf, rowsum);
  k_lse<<<2080, 256, 0, stream>>>(zn, rowsum);
  k_final<<<1, 1024, 0, stream>>>(rowsum, posbuf, out);
}